// Round 1
// baseline (4511.998 us; speedup 1.0000x reference)
//
#include <hip/hip_runtime.h>
#include <stdint.h>

#define NN 1024
#define FF 35
#define FP 36
#define HALF 512
#define LIN_IN 1610
#define NB 16

__device__ __forceinline__ float leakyf(float x) { return x >= 0.f ? x : 0.01f * x; }

// ---------------------------------------------------------------- codes: s(float 0..4) -> u8
__global__ __launch_bounds__(256)
void codes_kernel(const float* __restrict__ s, uint8_t* __restrict__ codes, int n4) {
    int i = blockIdx.x * 256 + threadIdx.x;
    for (; i < n4; i += gridDim.x * 256) {
        float4 v = ((const float4*)s)[i];
        uchar4 c;
        c.x = (uint8_t)v.x; c.y = (uint8_t)v.y; c.z = (uint8_t)v.z; c.w = (uint8_t)v.w;
        ((uchar4*)codes)[i] = c;
    }
}

// ---------------------------------------------------------------- one WLC step
// y[i,f] = x[i,f] + sum_j LUT[code_ij][f] * x[j,f],  LUT[0]=0, LUT[k]=Kt[k-1]
// wave = row, lane = j, 9 feature-quads in registers, x staged bf16 in LDS (2 phases)
__global__ __launch_bounds__(512)
void wlc_step(const float* __restrict__ xin_base, float* __restrict__ xout_base,
              const uint8_t* __restrict__ codes, const float* __restrict__ K,
              int nch, int inch_shift, int ich, int t, int do_leaky)
{
    __shared__ __align__(16) uint16_t xs[HALF * FP];
    __shared__ __align__(16) float lut[5 * 44];

    const int s    = blockIdx.z;
    const int ch   = blockIdx.y;
    const int wave = threadIdx.x >> 6;
    const int lane = threadIdx.x & 63;
    const int row  = blockIdx.x * 8 + wave;

    const int inch = ch >> inch_shift;
    const float* __restrict__ xin  = xin_base  + ((size_t)s * ich + inch) * (NN * FF);
    float*       __restrict__ xout = xout_base + ((size_t)s * nch + ch)   * (NN * FF);
    const uint8_t* __restrict__ crow = codes + ((size_t)s * NN + row) * NN;

    { // LUT: [5][44], row 0 and cols >=35 are zero
        const int kch = ch & 1;
        const float* Kt = K + ((size_t)(kch * 2 + t) * 4) * FF;
        for (int idx = threadIdx.x; idx < 5 * 44; idx += 512) {
            int k = idx / 44, f = idx - k * 44;
            lut[idx] = (k == 0 || f >= FF) ? 0.f : Kt[(k - 1) * FF + f];
        }
    }

    float acc[9][4];
#pragma unroll
    for (int a = 0; a < 9; ++a)
#pragma unroll
        for (int b = 0; b < 4; ++b) acc[a][b] = 0.f;

    for (int phase = 0; phase < 2; ++phase) {
        __syncthreads();
        for (int idx = threadIdx.x; idx < HALF * FP; idx += 512) {
            int j = idx / FP, c = idx - j * FP;
            float v = (c < FF) ? xin[(phase * HALF + j) * FF + c] : 0.f;
            xs[idx] = (uint16_t)((__float_as_uint(v) + 0x8000u) >> 16);  // bf16 rn-ish
        }
        __syncthreads();

        const uint8_t* cp = crow + phase * HALF + lane;
#pragma unroll
        for (int jit = 0; jit < 8; ++jit) {
            const unsigned code = cp[jit * 64];
            const float* lrow = &lut[code * 44];
            const uint16_t* xrow = &xs[(jit * 64 + lane) * FP];
#pragma unroll
            for (int fq = 0; fq < 9; ++fq) {
                float4 w = *(const float4*)(lrow + fq * 4);
                uint2 xv = *(const uint2*)(xrow + fq * 4);
                float x0 = __uint_as_float(xv.x << 16);
                float x1 = __uint_as_float(xv.x & 0xffff0000u);
                float x2 = __uint_as_float(xv.y << 16);
                float x3 = __uint_as_float(xv.y & 0xffff0000u);
                acc[fq][0] += w.x * x0;
                acc[fq][1] += w.y * x1;
                acc[fq][2] += w.z * x2;
                acc[fq][3] += w.w * x3;
            }
        }
    }

#pragma unroll
    for (int fq = 0; fq < 9; ++fq)
#pragma unroll
        for (int b = 0; b < 4; ++b) {
            const int f = fq * 4 + b;
            if (f >= FF) continue;
            float v = acc[fq][b];
#pragma unroll
            for (int o = 32; o >= 1; o >>= 1) v += __shfl_xor(v, o, 64);
            if (lane == 0) {
                float y = xin[row * FF + f] + v;
                xout[row * FF + f] = do_leaky ? leakyf(y) : y;
            }
        }
}

// ---------------------------------------------------------------- spp max over c2 (leaky'd)
__global__ __launch_bounds__(256)
void spp_max_kernel(const float* __restrict__ c2, float* __restrict__ h0)
{
    const int gw   = (blockIdx.x * 256 + threadIdx.x) >> 6;
    const int lane = threadIdx.x & 63;
    if (gw >= NB * 4 * 385) return;
    const int s    = gw / (4 * 385);
    int rem        = gw - s * (4 * 385);
    const int c    = rem / 385;
    const int cell = rem - c * 385;

    int p1 = 1, base = 0;
    while (p1 < 10 && cell >= base + p1 * p1) { base += p1 * p1; ++p1; }
    const int ci = cell - base;

    int kh = (NN + p1 - 1) / p1;  int ph = kh * p1 - NN; if (ph * 2 > kh) ph = kh / 2;
    int kw = (FF + p1 - 1) / p1;  int pw = kw * p1 - FF; if (pw * 2 > kw) pw = kw / 2;
    const int ow = (FF + 2 * pw - kw) / kw + 1;
    const int oh = (NN + 2 * ph - kh) / kh + 1;
    if (ci >= oh * ow) return;  // zero-pad cell (memset already wrote 0)

    const int r = ci / ow, cw = ci - r * ow;
    int r0 = r * kh - ph;  int r1 = r0 + kh; if (r1 > NN) r1 = NN; if (r0 < 0) r0 = 0;
    int c0 = cw * kw - pw; int c1 = c0 + kw; if (c1 > FF) c1 = FF; if (c0 < 0) c0 = 0;

    const float* bp = c2 + ((size_t)s * 4 + c) * (NN * FF);
    float m = -3.402823466e38f;
    const int cc = c0 + lane;
    const bool act = cc < c1;
    for (int rr = r0; rr < r1; ++rr)
        if (act) m = fmaxf(m, bp[rr * FF + cc]);
#pragma unroll
    for (int o = 32; o >= 1; o >>= 1) m = fmaxf(m, __shfl_xor(m, o, 64));
    if (lane == 0) h0[(size_t)s * LIN_IN + c * 385 + cell] = m;
}

// ---------------------------------------------------------------- fused conv1+conv2+avg pools
// tile 34x34 (divides 340/510/1020 -> each tile in exactly one bin per level)
__global__ __launch_bounds__(256)
void conv_pool_kernel(const float* __restrict__ sM,
                      const float* __restrict__ cw1, const float* __restrict__ cb1,
                      const float* __restrict__ cw2, const float* __restrict__ cb2,
                      float* __restrict__ h0)
{
    __shared__ float st[38 * 38];
    __shared__ float z1s[2][36 * 36];
    __shared__ float wsum[4][5];

    const int sidx = blockIdx.y;
    const int tile = blockIdx.x;
    const int th = (tile / 30) * 34;
    const int tw = (tile % 30) * 34;
    const float* sp = sM + (size_t)sidx * (NN * NN) + (size_t)th * NN + tw;

    for (int i = threadIdx.x; i < 38 * 38; i += 256) {
        int r = i / 38, c = i - r * 38;
        st[i] = sp[(size_t)r * NN + c];
    }
    __syncthreads();

    // z1: 216 threads = 36 cols x 6 rowgroups (6 rows each), sliding 3x3 window
    if (threadIdx.x < 216) {
        const int col = threadIdx.x % 36;
        const int r0  = (threadIdx.x / 36) * 6;
        float sr0[3], sr1[3], sr2[3];
#pragma unroll
        for (int c = 0; c < 3; ++c) {
            sr0[c] = st[(r0 + 0) * 38 + col + c];
            sr1[c] = st[(r0 + 1) * 38 + col + c];
            sr2[c] = st[(r0 + 2) * 38 + col + c];
        }
#pragma unroll
        for (int r = 0; r < 6; ++r) {
#pragma unroll
            for (int cch = 0; cch < 2; ++cch) {
                float a = cb1[cch];
#pragma unroll
                for (int c = 0; c < 3; ++c) {
                    a += sr0[c] * cw1[cch * 9 + 0 + c];
                    a += sr1[c] * cw1[cch * 9 + 3 + c];
                    a += sr2[c] * cw1[cch * 9 + 6 + c];
                }
                z1s[cch][(r0 + r) * 36 + col] = leakyf(a);
            }
            if (r < 5) {
#pragma unroll
                for (int c = 0; c < 3; ++c) {
                    sr0[c] = sr1[c]; sr1[c] = sr2[c];
                    sr2[c] = st[(r0 + r + 3) * 38 + col + c];
                }
            }
        }
    }
    __syncthreads();

    float local[5] = {0.f, 0.f, 0.f, 0.f, 0.f};
    // z2: 238 threads = 34 cols x 7 rowgroups (5 rows, last 4), sliding window
    if (threadIdx.x < 238) {
        const int col = threadIdx.x % 34;
        const int rg  = threadIdx.x / 34;
        const int r0  = rg * 5;
        const int nr  = (rg == 6) ? 4 : 5;
        float za[2][3], zb[2][3], zc[2][3];
#pragma unroll
        for (int cch = 0; cch < 2; ++cch)
#pragma unroll
            for (int c = 0; c < 3; ++c) {
                za[cch][c] = z1s[cch][(r0 + 0) * 36 + col + c];
                zb[cch][c] = z1s[cch][(r0 + 1) * 36 + col + c];
                zc[cch][c] = z1s[cch][(r0 + 2) * 36 + col + c];
            }
        for (int r = 0; r < nr; ++r) {
#pragma unroll
            for (int o = 0; o < 5; ++o) {
                float a = cb2[o];
#pragma unroll
                for (int cch = 0; cch < 2; ++cch) {
                    const float* w = cw2 + (o * 2 + cch) * 9;
#pragma unroll
                    for (int c = 0; c < 3; ++c) {
                        a += za[cch][c] * w[c];
                        a += zb[cch][c] * w[3 + c];
                        a += zc[cch][c] * w[6 + c];
                    }
                }
                local[o] += leakyf(a);
            }
            if (r < nr - 1) {
#pragma unroll
                for (int cch = 0; cch < 2; ++cch)
#pragma unroll
                    for (int c = 0; c < 3; ++c) {
                        za[cch][c] = zb[cch][c]; zb[cch][c] = zc[cch][c];
                        zc[cch][c] = z1s[cch][(r0 + r + 3) * 36 + col + c];
                    }
            }
        }
    }

    const int wave = threadIdx.x >> 6, lane = threadIdx.x & 63;
#pragma unroll
    for (int o = 0; o < 5; ++o) {
        float v = local[o];
#pragma unroll
        for (int d = 32; d >= 1; d >>= 1) v += __shfl_xor(v, d, 64);
        if (lane == 0) wsum[wave][o] = v;
    }
    __syncthreads();
    if (threadIdx.x < 5) {
        const int o = threadIdx.x;
        const float tot = wsum[0][o] + wsum[1][o] + wsum[2][o] + wsum[3][o];
        const int b2 = (th / 510) * 2 + (tw / 510);
        const int b3 = (th / 340) * 3 + (tw / 340);
        float* dst = h0 + (size_t)sidx * LIN_IN + 1540 + o * 14;
        atomicAdd(dst + 0, tot);
        atomicAdd(dst + 1 + b2, tot);
        atomicAdd(dst + 5 + b3, tot);
    }
}

__global__ __launch_bounds__(256)
void stru_div_kernel(float* __restrict__ h0)
{
    const int i = blockIdx.x * 256 + threadIdx.x;
    if (i >= NB * 5 * 14) return;
    const int s = i / (5 * 14);
    const int rest = i - s * (5 * 14);
    const int within = rest % 14;
    const float d = (within == 0) ? (1.f / (1020.f * 1020.f))
                  : (within < 5)  ? (1.f / (510.f * 510.f))
                                  : (1.f / (340.f * 340.f));
    h0[(size_t)s * LIN_IN + 1540 + rest] *= d;
}

// ---------------------------------------------------------------- FC: out[b,o] = act(in[b,:] . W[o,:] + bias[o])
__global__ __launch_bounds__(256)
void fc_kernel(const float* __restrict__ in, const float* __restrict__ W,
               const float* __restrict__ bias, float* __restrict__ out,
               int K, int Nout, int do_leaky)
{
    const int o = (blockIdx.x * 256 + threadIdx.x) >> 6;
    const int lane = threadIdx.x & 63;
    if (o >= Nout) return;
    const float* wrow = W + (size_t)o * K;
    float acc[16];
#pragma unroll
    for (int b = 0; b < 16; ++b) acc[b] = 0.f;
    for (int k0 = 0; k0 < K; k0 += 64) {
        const int kk = k0 + lane;
        const bool in_r = kk < K;
        const float wv = in_r ? wrow[kk] : 0.f;
#pragma unroll
        for (int b = 0; b < 16; ++b) {
            const float hv = in_r ? in[(size_t)b * K + kk] : 0.f;
            acc[b] += wv * hv;
        }
    }
    float res = 0.f;
#pragma unroll
    for (int b = 0; b < 16; ++b) {
        float v = acc[b];
#pragma unroll
        for (int od = 32; od >= 1; od >>= 1) v += __shfl_xor(v, od, 64);
        if (lane == b) res = v;
    }
    if (lane < 16) {
        const float y = res + bias[o];
        out[(size_t)lane * Nout + o] = do_leaky ? leakyf(y) : y;
    }
}

// ---------------------------------------------------------------- launch
extern "C" void kernel_launch(void* const* d_in, const int* in_sizes, int n_in,
                              void* d_out, int out_size, void* d_ws, size_t ws_size,
                              hipStream_t stream)
{
    const float* labels = (const float*)d_in[0];
    const float* sM     = (const float*)d_in[1];
    const float* K1     = (const float*)d_in[2];
    const float* K2     = (const float*)d_in[3];
    const float* cw1    = (const float*)d_in[4];
    const float* cb1    = (const float*)d_in[5];
    const float* cw2    = (const float*)d_in[6];
    const float* cb2    = (const float*)d_in[7];
    const float* W1     = (const float*)d_in[8];
    const float* b1     = (const float*)d_in[9];
    const float* W2     = (const float*)d_in[10];
    const float* b2     = (const float*)d_in[11];
    const float* W3     = (const float*)d_in[12];
    const float* b3     = (const float*)d_in[13];
    const float* W4     = (const float*)d_in[14];
    const float* b4     = (const float*)d_in[15];
    const float* W5     = (const float*)d_in[16];
    const float* b5     = (const float*)d_in[17];

    char* ws = (char*)d_ws;
    uint8_t* codes = (uint8_t*)ws;  ws += (size_t)16 * 1024 * 1024;           // 16.78 MB
    float* bufA = (float*)ws;       ws += (size_t)16 * 4 * 1024 * 35 * 4;     // 9.18 MB
    float* bufB = (float*)ws;       ws += (size_t)16 * 4 * 1024 * 35 * 4;     // 9.18 MB
    float* h0   = (float*)ws;       ws += ((size_t)16 * 1610 * 4 + 255) / 256 * 256;
    float* hA   = (float*)ws;       ws += (size_t)16 * 2000 * 4;
    float* hB   = (float*)ws;       ws += (size_t)16 * 2000 * 4;

    hipMemsetAsync(h0, 0, (size_t)16 * LIN_IN * 4, stream);

    codes_kernel<<<2048, 256, 0, stream>>>(sM, codes, 16 * 1024 * 1024 / 4);

    // WLC: c1 (2 ch, t=0,1) then c2 (4 ch, t=0,1); leaky on final t of each
    wlc_step<<<dim3(128, 2, 16), 512, 0, stream>>>(labels, bufA, codes, K1, 2, 1, 1, 0, 0);
    wlc_step<<<dim3(128, 2, 16), 512, 0, stream>>>(bufA,   bufB, codes, K1, 2, 0, 2, 1, 1);
    wlc_step<<<dim3(128, 4, 16), 512, 0, stream>>>(bufB,   bufA, codes, K2, 4, 1, 2, 0, 0);
    wlc_step<<<dim3(128, 4, 16), 512, 0, stream>>>(bufA,   bufB, codes, K2, 4, 0, 4, 1, 1);

    spp_max_kernel<<<6160, 256, 0, stream>>>(bufB, h0);
    conv_pool_kernel<<<dim3(900, 16), 256, 0, stream>>>(sM, cw1, cb1, cw2, cb2, h0);
    stru_div_kernel<<<5, 256, 0, stream>>>(h0);

    fc_kernel<<<500, 256, 0, stream>>>(h0, W1, b1, hA, LIN_IN, 2000, 1);
    fc_kernel<<<500, 256, 0, stream>>>(hA, W2, b2, hB, 2000, 2000, 1);
    fc_kernel<<<500, 256, 0, stream>>>(hB, W3, b3, hA, 2000, 2000, 1);
    fc_kernel<<<500, 256, 0, stream>>>(hA, W4, b4, hB, 2000, 2000, 1);
    fc_kernel<<<1,   256, 0, stream>>>(hB, W5, b5, (float*)d_out, 2000, 2, 0);
}

// Round 3
// 606.357 us; speedup vs baseline: 7.4412x; 7.4412x over previous
//
#include <hip/hip_runtime.h>
#include <stdint.h>

#define NN 1024
#define FF 35
#define LIN_IN 1610
#define NB 16

typedef short short8 __attribute__((ext_vector_type(8)));
typedef float f32x4 __attribute__((ext_vector_type(4)));

__device__ __forceinline__ float leakyf(float x) { return x >= 0.f ? x : 0.01f * x; }
__device__ __forceinline__ uint16_t to_bf16(float v) {
    return (uint16_t)((__float_as_uint(v) + 0x8000u) >> 16);
}

// ---------------------------------------------------------------- codes: s(float 0..4) -> u8
__global__ __launch_bounds__(256)
void codes_kernel(const float* __restrict__ s, uint8_t* __restrict__ codes, int n4) {
    int i = blockIdx.x * 256 + threadIdx.x;
    for (; i < n4; i += gridDim.x * 256) {
        float4 v = ((const float4*)s)[i];
        uchar4 c;
        c.x = (uint8_t)v.x; c.y = (uint8_t)v.y; c.z = (uint8_t)v.z; c.w = (uint8_t)v.w;
        ((uchar4*)codes)[i] = c;
    }
}

// ---------------------------------------------------------------- labels [16][1024][35] f32 -> XT0 bf16 [16][48][1024] + XR0 f32 (f>=35 zero)
__global__ __launch_bounds__(256)
void labels_to_xt(const float* __restrict__ labels, uint16_t* __restrict__ XT0,
                  float* __restrict__ XR0)
{
    __shared__ float buf[256 * FF];
    const int s = blockIdx.x;
    const int i0 = blockIdx.y * 256;
    const float* src = labels + ((size_t)s * NN + i0) * FF;
    for (int t = threadIdx.x; t < 256 * FF; t += 256) buf[t] = src[t];
    __syncthreads();
    for (int f = 0; f < 48; ++f) {
        const int ii = threadIdx.x;
        float v = (f < FF) ? buf[ii * FF + f] : 0.f;
        size_t o = ((size_t)s * 48 + f) * 1024 + i0 + ii;
        XR0[o] = v;
        XT0[o] = to_bf16(v);
    }
}

// ---------------------------------------------------------------- one-hot A-fragment expansion
// cd = 8 code bytes (j..j+7); returns 8 bf16: (code==k+1) ? 1.0 : 0.0
// Borrow-free per-byte zero detect: a byte of (y&0x7F)+0x7F can never carry
// into the next byte, so this is an exact per-byte mask (the classic
// (y-0x01010101)&~y&0x80808080 haszero trick is NOT: a zero byte's borrow
// corrupts the next byte's flag).
__device__ __forceinline__ short8 expand_onehot(uint2 cd, uint32_t dupK) {
    union { uint32_t u[4]; short8 v; } r;
#pragma unroll
    for (int h = 0; h < 2; ++h) {
        uint32_t d = h ? cd.y : cd.x;
        uint32_t y = d ^ dupK;
        uint32_t m = (~(((y & 0x7F7F7F7Fu) + 0x7F7F7F7Fu) | y)) & 0x80808080u;
        uint32_t m2 = m >> 7;                               // 0x01 at matched bytes
        r.u[h * 2 + 0] = ((m2 & 0xFFu) | ((m2 & 0xFF00u) << 8)) * 0x3F80u;
        r.u[h * 2 + 1] = (((m2 >> 16) & 0xFFu) | ((m2 >> 8) & 0xFF0000u)) * 0x3F80u;
    }
    return r.v;
}

// ---------------------------------------------------------------- WLC step as MFMA GEMM
// y[i, ch*48+f] = xr_in[inch][f][i] + sum_k Kt[kch,t][k,f] * sum_j (code_ij==k+1) * xt_in[inch][f][j]
// block: 64(M=i) x 96(N=ch*48+f); 4 waves stacked on M (wave tile 16x96); K-loop: 16 j-tiles x 4 k
__global__ __launch_bounds__(256, 2)
void wlc_gemm(const uint16_t* __restrict__ XT_in, const float* __restrict__ XR_in,
              uint16_t* __restrict__ XT_out, float* __restrict__ XR_out,
              const uint8_t* __restrict__ codes, const float* __restrict__ Kg,
              int t, int shift, int nch_in, int nch_out, int do_leaky)
{
    __shared__ __align__(16) uint16_t xs[96 * 64];

    const int s   = blockIdx.z;
    const int mt  = blockIdx.x;
    const int nt  = blockIdx.y;
    const int tid = threadIdx.x;
    const int wid = tid >> 6;
    const int lane = tid & 63;
    const int i0 = mt * 64;

    // staging: 96 rows x 64 bf16, 768 16B-units, 3 per thread; XOR-swizzled dest
    const uint16_t* srcp[3];
    uint16_t* dstp[3];
#pragma unroll
    for (int it = 0; it < 3; ++it) {
        int u = it * 256 + tid;
        int r = u >> 3, c8 = u & 7;
        int hi = (r >= 48);
        int chout_r = nt * 2 + hi;
        int f_r = r - 48 * hi;
        int inch_r = chout_r >> shift;
        srcp[it] = XT_in + (((size_t)s * nch_in + inch_r) * 48 + f_r) * 1024 + c8 * 8;
        dstp[it] = &xs[r * 64 + ((c8 ^ (r & 7)) * 8)];
    }

    const uint8_t* cbase = codes + ((size_t)s << 20)
        + (size_t)(i0 + wid * 16 + (lane & 15)) * 1024 + ((lane >> 4) << 3);

    f32x4 acc[4][6];
#pragma unroll
    for (int k = 0; k < 4; ++k)
#pragma unroll
        for (int nf = 0; nf < 6; ++nf) acc[k][nf] = (f32x4){0.f, 0.f, 0.f, 0.f};

    for (int jt = 0; jt < 16; ++jt) {
        const int j0 = jt * 64;
        __syncthreads();
#pragma unroll
        for (int it = 0; it < 3; ++it) {
            uint4 v = *(const uint4*)(srcp[it] + j0);
            *(uint4*)dstp[it] = v;
        }
        __syncthreads();

        const uint2 cd0 = *(const uint2*)(cbase + j0);
        const uint2 cd1 = *(const uint2*)(cbase + j0 + 32);

        short8 bfr[6][2];
#pragma unroll
        for (int nf = 0; nf < 6; ++nf)
#pragma unroll
            for (int kk = 0; kk < 2; ++kk) {
                int n = nf * 16 + (lane & 15);
                int c8 = kk * 4 + (lane >> 4);
                bfr[nf][kk] = *(const short8*)&xs[n * 64 + ((c8 ^ (n & 7)) * 8)];
            }

#pragma unroll
        for (int k = 0; k < 4; ++k) {
            const uint32_t dupK = 0x01010101u * (k + 1);
#pragma unroll
            for (int kk = 0; kk < 2; ++kk) {
                short8 af = expand_onehot(kk ? cd1 : cd0, dupK);
#pragma unroll
                for (int nf = 0; nf < 6; ++nf)
                    acc[k][nf] = __builtin_amdgcn_mfma_f32_16x16x32_bf16(
                        af, bfr[nf][kk], acc[k][nf], 0, 0, 0);
            }
        }
    }

    // epilogue: fold Kt scales, add residual, leaky, store f32 + bf16 (both [ch][48][1024])
    float sc[4][6];
#pragma unroll
    for (int nf = 0; nf < 6; ++nf) {
        int fnl = (nf % 3) * 16 + (lane & 15);
        int chout = nt * 2 + nf / 3;
        int kch = chout & 1;
#pragma unroll
        for (int k = 0; k < 4; ++k)
            sc[k][nf] = (fnl < FF) ? Kg[((kch * 2 + t) * 4 + k) * FF + fnl] : 0.f;
    }

#pragma unroll
    for (int nf = 0; nf < 6; ++nf) {
        int fnl = (nf % 3) * 16 + (lane & 15);
        int chout = nt * 2 + nf / 3;
        int inch = chout >> shift;
        int irow = i0 + wid * 16 + ((lane >> 4) << 2);
        f32x4 rr = sc[0][nf] * acc[0][nf];
        rr += sc[1][nf] * acc[1][nf];
        rr += sc[2][nf] * acc[2][nf];
        rr += sc[3][nf] * acc[3][nf];
        size_t rb = (((size_t)s * nch_in + inch) * 48 + fnl) * 1024 + irow;
        float4 rd = *(const float4*)&XR_in[rb];
        float y0 = rr.x + rd.x, y1 = rr.y + rd.y, y2 = rr.z + rd.z, y3 = rr.w + rd.w;
        if (do_leaky) { y0 = leakyf(y0); y1 = leakyf(y1); y2 = leakyf(y2); y3 = leakyf(y3); }
        size_t ob = (((size_t)s * nch_out + chout) * 48 + fnl) * 1024 + irow;
        *(float4*)&XR_out[ob] = make_float4(y0, y1, y2, y3);
        ushort4 bv;
        bv.x = to_bf16(y0); bv.y = to_bf16(y1); bv.z = to_bf16(y2); bv.w = to_bf16(y3);
        *(ushort4*)&XT_out[ob] = bv;
    }
}

// ---------------------------------------------------------------- spp max over c2 (transposed layout [s][c][48][1024])
__global__ __launch_bounds__(256)
void spp_max_kernel(const float* __restrict__ xr4, float* __restrict__ h0)
{
    const int gw   = (blockIdx.x * 256 + threadIdx.x) >> 6;
    const int lane = threadIdx.x & 63;
    if (gw >= NB * 4 * 385) return;
    const int s    = gw / (4 * 385);
    int rem        = gw - s * (4 * 385);
    const int c    = rem / 385;
    const int cell = rem - c * 385;

    int p1 = 1, base = 0;
    while (p1 < 10 && cell >= base + p1 * p1) { base += p1 * p1; ++p1; }
    const int ci = cell - base;

    int kh = (NN + p1 - 1) / p1;  int ph = kh * p1 - NN; if (ph * 2 > kh) ph = kh / 2;
    int kw = (FF + p1 - 1) / p1;  int pw = kw * p1 - FF; if (pw * 2 > kw) pw = kw / 2;
    const int ow = (FF + 2 * pw - kw) / kw + 1;
    const int oh = (NN + 2 * ph - kh) / kh + 1;
    if (ci >= oh * ow) return;  // zero-pad cell (memset already wrote 0)

    const int r = ci / ow, cw = ci - r * ow;
    int r0 = r * kh - ph;  int r1 = r0 + kh; if (r1 > NN) r1 = NN; if (r0 < 0) r0 = 0;
    int c0 = cw * kw - pw; int c1 = c0 + kw; if (c1 > FF) c1 = FF; if (c0 < 0) c0 = 0;

    const float* bp = xr4 + ((size_t)s * 4 + c) * (48 * 1024);
    float m = -3.402823466e38f;
    for (int ff = c0; ff < c1; ++ff) {
        const float* rowp = bp + (size_t)ff * 1024;
        for (int ii = r0 + lane; ii < r1; ii += 64) m = fmaxf(m, rowp[ii]);
    }
#pragma unroll
    for (int o = 32; o >= 1; o >>= 1) m = fmaxf(m, __shfl_xor(m, o, 64));
    if (lane == 0) h0[(size_t)s * LIN_IN + c * 385 + cell] = m;
}

// ---------------------------------------------------------------- fused conv1+conv2+avg pools
__global__ __launch_bounds__(256)
void conv_pool_kernel(const float* __restrict__ sM,
                      const float* __restrict__ cw1, const float* __restrict__ cb1,
                      const float* __restrict__ cw2, const float* __restrict__ cb2,
                      float* __restrict__ h0)
{
    __shared__ float st[38 * 38];
    __shared__ float z1s[2][36 * 36];
    __shared__ float wsum[4][5];

    const int sidx = blockIdx.y;
    const int tile = blockIdx.x;
    const int th = (tile / 30) * 34;
    const int tw = (tile % 30) * 34;
    const float* sp = sM + (size_t)sidx * (NN * NN) + (size_t)th * NN + tw;

    for (int i = threadIdx.x; i < 38 * 38; i += 256) {
        int r = i / 38, c = i - r * 38;
        st[i] = sp[(size_t)r * NN + c];
    }
    __syncthreads();

    if (threadIdx.x < 216) {
        const int col = threadIdx.x % 36;
        const int r0  = (threadIdx.x / 36) * 6;
        float sr0[3], sr1[3], sr2[3];
#pragma unroll
        for (int c = 0; c < 3; ++c) {
            sr0[c] = st[(r0 + 0) * 38 + col + c];
            sr1[c] = st[(r0 + 1) * 38 + col + c];
            sr2[c] = st[(r0 + 2) * 38 + col + c];
        }
#pragma unroll
        for (int r = 0; r < 6; ++r) {
#pragma unroll
            for (int cch = 0; cch < 2; ++cch) {
                float a = cb1[cch];
#pragma unroll
                for (int c = 0; c < 3; ++c) {
                    a += sr0[c] * cw1[cch * 9 + 0 + c];
                    a += sr1[c] * cw1[cch * 9 + 3 + c];
                    a += sr2[c] * cw1[cch * 9 + 6 + c];
                }
                z1s[cch][(r0 + r) * 36 + col] = leakyf(a);
            }
            if (r < 5) {
#pragma unroll
                for (int c = 0; c < 3; ++c) {
                    sr0[c] = sr1[c]; sr1[c] = sr2[c];
                    sr2[c] = st[(r0 + r + 3) * 38 + col + c];
                }
            }
        }
    }
    __syncthreads();

    float local[5] = {0.f, 0.f, 0.f, 0.f, 0.f};
    if (threadIdx.x < 238) {
        const int col = threadIdx.x % 34;
        const int rg  = threadIdx.x / 34;
        const int r0  = rg * 5;
        const int nr  = (rg == 6) ? 4 : 5;
        float za[2][3], zb[2][3], zc[2][3];
#pragma unroll
        for (int cch = 0; cch < 2; ++cch)
#pragma unroll
            for (int c = 0; c < 3; ++c) {
                za[cch][c] = z1s[cch][(r0 + 0) * 36 + col + c];
                zb[cch][c] = z1s[cch][(r0 + 1) * 36 + col + c];
                zc[cch][c] = z1s[cch][(r0 + 2) * 36 + col + c];
            }
        for (int r = 0; r < nr; ++r) {
#pragma unroll
            for (int o = 0; o < 5; ++o) {
                float a = cb2[o];
#pragma unroll
                for (int cch = 0; cch < 2; ++cch) {
                    const float* w = cw2 + (o * 2 + cch) * 9;
#pragma unroll
                    for (int c = 0; c < 3; ++c) {
                        a += za[cch][c] * w[c];
                        a += zb[cch][c] * w[3 + c];
                        a += zc[cch][c] * w[6 + c];
                    }
                }
                local[o] += leakyf(a);
            }
            if (r < nr - 1) {
#pragma unroll
                for (int cch = 0; cch < 2; ++cch)
#pragma unroll
                    for (int c = 0; c < 3; ++c) {
                        za[cch][c] = zb[cch][c]; zb[cch][c] = zc[cch][c];
                        zc[cch][c] = z1s[cch][(r0 + r + 3) * 36 + col + c];
                    }
            }
        }
    }

    const int wave = threadIdx.x >> 6, lane = threadIdx.x & 63;
#pragma unroll
    for (int o = 0; o < 5; ++o) {
        float v = local[o];
#pragma unroll
        for (int d = 32; d >= 1; d >>= 1) v += __shfl_xor(v, d, 64);
        if (lane == 0) wsum[wave][o] = v;
    }
    __syncthreads();
    if (threadIdx.x < 5) {
        const int o = threadIdx.x;
        const float tot = wsum[0][o] + wsum[1][o] + wsum[2][o] + wsum[3][o];
        const int b2 = (th / 510) * 2 + (tw / 510);
        const int b3 = (th / 340) * 3 + (tw / 340);
        float* dst = h0 + (size_t)sidx * LIN_IN + 1540 + o * 14;
        atomicAdd(dst + 0, tot);
        atomicAdd(dst + 1 + b2, tot);
        atomicAdd(dst + 5 + b3, tot);
    }
}

__global__ __launch_bounds__(256)
void stru_div_kernel(float* __restrict__ h0)
{
    const int i = blockIdx.x * 256 + threadIdx.x;
    if (i >= NB * 5 * 14) return;
    const int s = i / (5 * 14);
    const int rest = i - s * (5 * 14);
    const int within = rest % 14;
    const float d = (within == 0) ? (1.f / (1020.f * 1020.f))
                  : (within < 5)  ? (1.f / (510.f * 510.f))
                                  : (1.f / (340.f * 340.f));
    h0[(size_t)s * LIN_IN + 1540 + rest] *= d;
}

// ---------------------------------------------------------------- FC
__global__ __launch_bounds__(256)
void fc_kernel(const float* __restrict__ in, const float* __restrict__ W,
               const float* __restrict__ bias, float* __restrict__ out,
               int K, int Nout, int do_leaky)
{
    const int o = (blockIdx.x * 256 + threadIdx.x) >> 6;
    const int lane = threadIdx.x & 63;
    if (o >= Nout) return;
    const float* wrow = W + (size_t)o * K;
    float acc[16];
#pragma unroll
    for (int b = 0; b < 16; ++b) acc[b] = 0.f;
    for (int k0 = 0; k0 < K; k0 += 64) {
        const int kk = k0 + lane;
        const bool in_r = kk < K;
        const float wv = in_r ? wrow[kk] : 0.f;
#pragma unroll
        for (int b = 0; b < 16; ++b) {
            const float hv = in_r ? in[(size_t)b * K + kk] : 0.f;
            acc[b] += wv * hv;
        }
    }
    float res = 0.f;
#pragma unroll
    for (int b = 0; b < 16; ++b) {
        float v = acc[b];
#pragma unroll
        for (int od = 32; od >= 1; od >>= 1) v += __shfl_xor(v, od, 64);
        if (lane == b) res = v;
    }
    if (lane < 16) {
        const float y = res + bias[o];
        out[(size_t)lane * Nout + o] = do_leaky ? leakyf(y) : y;
    }
}

// ---------------------------------------------------------------- launch
extern "C" void kernel_launch(void* const* d_in, const int* in_sizes, int n_in,
                              void* d_out, int out_size, void* d_ws, size_t ws_size,
                              hipStream_t stream)
{
    const float* labels = (const float*)d_in[0];
    const float* sM     = (const float*)d_in[1];
    const float* K1     = (const float*)d_in[2];
    const float* K2     = (const float*)d_in[3];
    const float* cw1    = (const float*)d_in[4];
    const float* cb1    = (const float*)d_in[5];
    const float* cw2    = (const float*)d_in[6];
    const float* cb2    = (const float*)d_in[7];
    const float* W1     = (const float*)d_in[8];
    const float* b1     = (const float*)d_in[9];
    const float* W2     = (const float*)d_in[10];
    const float* b2     = (const float*)d_in[11];
    const float* W3     = (const float*)d_in[12];
    const float* b3     = (const float*)d_in[13];
    const float* W4     = (const float*)d_in[14];
    const float* b4     = (const float*)d_in[15];
    const float* W5     = (const float*)d_in[16];
    const float* b5     = (const float*)d_in[17];

    char* ws = (char*)d_ws;
    uint8_t* codes = (uint8_t*)ws;  ws += (size_t)16 << 20;        // 16 MB
    char* ping = ws;                ws += 18874368;                 // XT(6.29MB) + XR(12.58MB)
    char* pong = ws;                ws += 18874368;
    float* h0  = (float*)ws;        ws += 103168;
    float* hA  = (float*)ws;        ws += 128000;
    float* hB  = (float*)ws;        ws += 128000;

    uint16_t* XTp = (uint16_t*)ping; float* XRp = (float*)(ping + 6291456);
    uint16_t* XTq = (uint16_t*)pong; float* XRq = (float*)(pong + 6291456);

    hipMemsetAsync(h0, 0, (size_t)NB * LIN_IN * 4, stream);

    codes_kernel<<<2048, 256, 0, stream>>>(sM, codes, 16 * 1024 * 1024 / 4);
    labels_to_xt<<<dim3(16, 4), 256, 0, stream>>>(labels, XTq, XRq);

    // 4 sequential WLC stages as MFMA GEMMs
    wlc_gemm<<<dim3(16, 1, 16), 256, 0, stream>>>(XTq, XRq, XTp, XRp, codes, K1, 0, 1, 1, 2, 0);
    wlc_gemm<<<dim3(16, 1, 16), 256, 0, stream>>>(XTp, XRp, XTq, XRq, codes, K1, 1, 0, 2, 2, 1);
    wlc_gemm<<<dim3(16, 2, 16), 256, 0, stream>>>(XTq, XRq, XTp, XRp, codes, K2, 0, 1, 2, 4, 0);
    wlc_gemm<<<dim3(16, 2, 16), 256, 0, stream>>>(XTp, XRp, XTq, XRq, codes, K2, 1, 0, 4, 4, 1);

    spp_max_kernel<<<6160, 256, 0, stream>>>(XRq, h0);
    conv_pool_kernel<<<dim3(900, 16), 256, 0, stream>>>(sM, cw1, cb1, cw2, cb2, h0);
    stru_div_kernel<<<5, 256, 0, stream>>>(h0);

    fc_kernel<<<500, 256, 0, stream>>>(h0, W1, b1, hA, LIN_IN, 2000, 1);
    fc_kernel<<<500, 256, 0, stream>>>(hA, W2, b2, hB, 2000, 2000, 1);
    fc_kernel<<<500, 256, 0, stream>>>(hB, W3, b3, hA, 2000, 2000, 1);
    fc_kernel<<<500, 256, 0, stream>>>(hA, W4, b4, hB, 2000, 2000, 1);
    fc_kernel<<<1,   256, 0, stream>>>(hB, W5, b5, (float*)d_out, 2000, 2, 0);
}

// Round 4
// 478.479 us; speedup vs baseline: 9.4299x; 1.2673x over previous
//
#include <hip/hip_runtime.h>
#include <stdint.h>

#define NN 1024
#define FF 35
#define LIN_IN 1610
#define NB 16

typedef short short8 __attribute__((ext_vector_type(8)));
typedef float f32x4 __attribute__((ext_vector_type(4)));

__device__ __forceinline__ float leakyf(float x) { return x >= 0.f ? x : 0.01f * x; }
__device__ __forceinline__ uint16_t to_bf16(float v) {
    return (uint16_t)((__float_as_uint(v) + 0x8000u) >> 16);
}

// ---------------------------------------------------------------- codes: s(float 0..4) -> u8
__global__ __launch_bounds__(256)
void codes_kernel(const float* __restrict__ s, uint8_t* __restrict__ codes, int n4) {
    int i = blockIdx.x * 256 + threadIdx.x;
    for (; i < n4; i += gridDim.x * 256) {
        float4 v = ((const float4*)s)[i];
        uchar4 c;
        c.x = (uint8_t)v.x; c.y = (uint8_t)v.y; c.z = (uint8_t)v.z; c.w = (uint8_t)v.w;
        ((uchar4*)codes)[i] = c;
    }
}

// ---------------------------------------------------------------- labels [16][1024][35] f32 -> XT0 bf16 [16][48][1024] + XR0 f32 (f>=35 zero)
__global__ __launch_bounds__(256)
void labels_to_xt(const float* __restrict__ labels, uint16_t* __restrict__ XT0,
                  float* __restrict__ XR0)
{
    __shared__ float buf[256 * FF];
    const int s = blockIdx.x;
    const int i0 = blockIdx.y * 256;
    const float* src = labels + ((size_t)s * NN + i0) * FF;
    for (int t = threadIdx.x; t < 256 * FF; t += 256) buf[t] = src[t];
    __syncthreads();
    for (int f = 0; f < 48; ++f) {
        const int ii = threadIdx.x;
        float v = (f < FF) ? buf[ii * FF + f] : 0.f;
        size_t o = ((size_t)s * 48 + f) * 1024 + i0 + ii;
        XR0[o] = v;
        XT0[o] = to_bf16(v);
    }
}

// ---------------------------------------------------------------- one-hot A-fragment expansion
// Borrow-free per-byte zero detect (exact per-byte mask; the classic
// (y-0x01010101)&~y&0x80808080 haszero trick is NOT per-byte-exact).
__device__ __forceinline__ short8 expand_onehot(uint2 cd, uint32_t dupK) {
    union { uint32_t u[4]; short8 v; } r;
#pragma unroll
    for (int h = 0; h < 2; ++h) {
        uint32_t d = h ? cd.y : cd.x;
        uint32_t y = d ^ dupK;
        uint32_t m = (~(((y & 0x7F7F7F7Fu) + 0x7F7F7F7Fu) | y)) & 0x80808080u;
        uint32_t m2 = m >> 7;                               // 0x01 at matched bytes
        r.u[h * 2 + 0] = ((m2 & 0xFFu) | ((m2 & 0xFF00u) << 8)) * 0x3F80u;
        r.u[h * 2 + 1] = (((m2 >> 16) & 0xFFu) | ((m2 >> 8) & 0xFF0000u)) * 0x3F80u;
    }
    return r.v;
}

// ---------------------------------------------------------------- WLC step as MFMA GEMM
__global__ __launch_bounds__(256, 2)
void wlc_gemm(const uint16_t* __restrict__ XT_in, const float* __restrict__ XR_in,
              uint16_t* __restrict__ XT_out, float* __restrict__ XR_out,
              const uint8_t* __restrict__ codes, const float* __restrict__ Kg,
              int t, int shift, int nch_in, int nch_out, int do_leaky)
{
    __shared__ __align__(16) uint16_t xs[96 * 64];

    const int s   = blockIdx.z;
    const int mt  = blockIdx.x;
    const int nt  = blockIdx.y;
    const int tid = threadIdx.x;
    const int wid = tid >> 6;
    const int lane = tid & 63;
    const int i0 = mt * 64;

    const uint16_t* srcp[3];
    uint16_t* dstp[3];
#pragma unroll
    for (int it = 0; it < 3; ++it) {
        int u = it * 256 + tid;
        int r = u >> 3, c8 = u & 7;
        int hi = (r >= 48);
        int chout_r = nt * 2 + hi;
        int f_r = r - 48 * hi;
        int inch_r = chout_r >> shift;
        srcp[it] = XT_in + (((size_t)s * nch_in + inch_r) * 48 + f_r) * 1024 + c8 * 8;
        dstp[it] = &xs[r * 64 + ((c8 ^ (r & 7)) * 8)];
    }

    const uint8_t* cbase = codes + ((size_t)s << 20)
        + (size_t)(i0 + wid * 16 + (lane & 15)) * 1024 + ((lane >> 4) << 3);

    f32x4 acc[4][6];
#pragma unroll
    for (int k = 0; k < 4; ++k)
#pragma unroll
        for (int nf = 0; nf < 6; ++nf) acc[k][nf] = (f32x4){0.f, 0.f, 0.f, 0.f};

    for (int jt = 0; jt < 16; ++jt) {
        const int j0 = jt * 64;
        __syncthreads();
#pragma unroll
        for (int it = 0; it < 3; ++it) {
            uint4 v = *(const uint4*)(srcp[it] + j0);
            *(uint4*)dstp[it] = v;
        }
        __syncthreads();

        const uint2 cd0 = *(const uint2*)(cbase + j0);
        const uint2 cd1 = *(const uint2*)(cbase + j0 + 32);

        short8 bfr[6][2];
#pragma unroll
        for (int nf = 0; nf < 6; ++nf)
#pragma unroll
            for (int kk = 0; kk < 2; ++kk) {
                int n = nf * 16 + (lane & 15);
                int c8 = kk * 4 + (lane >> 4);
                bfr[nf][kk] = *(const short8*)&xs[n * 64 + ((c8 ^ (n & 7)) * 8)];
            }

#pragma unroll
        for (int k = 0; k < 4; ++k) {
            const uint32_t dupK = 0x01010101u * (k + 1);
#pragma unroll
            for (int kk = 0; kk < 2; ++kk) {
                short8 af = expand_onehot(kk ? cd1 : cd0, dupK);
#pragma unroll
                for (int nf = 0; nf < 6; ++nf)
                    acc[k][nf] = __builtin_amdgcn_mfma_f32_16x16x32_bf16(
                        af, bfr[nf][kk], acc[k][nf], 0, 0, 0);
            }
        }
    }

    float sc[4][6];
#pragma unroll
    for (int nf = 0; nf < 6; ++nf) {
        int fnl = (nf % 3) * 16 + (lane & 15);
        int chout = nt * 2 + nf / 3;
        int kch = chout & 1;
#pragma unroll
        for (int k = 0; k < 4; ++k)
            sc[k][nf] = (fnl < FF) ? Kg[((kch * 2 + t) * 4 + k) * FF + fnl] : 0.f;
    }

#pragma unroll
    for (int nf = 0; nf < 6; ++nf) {
        int fnl = (nf % 3) * 16 + (lane & 15);
        int chout = nt * 2 + nf / 3;
        int inch = chout >> shift;
        int irow = i0 + wid * 16 + ((lane >> 4) << 2);
        f32x4 rr = sc[0][nf] * acc[0][nf];
        rr += sc[1][nf] * acc[1][nf];
        rr += sc[2][nf] * acc[2][nf];
        rr += sc[3][nf] * acc[3][nf];
        size_t rb = (((size_t)s * nch_in + inch) * 48 + fnl) * 1024 + irow;
        float4 rd = *(const float4*)&XR_in[rb];
        float y0 = rr.x + rd.x, y1 = rr.y + rd.y, y2 = rr.z + rd.z, y3 = rr.w + rd.w;
        if (do_leaky) { y0 = leakyf(y0); y1 = leakyf(y1); y2 = leakyf(y2); y3 = leakyf(y3); }
        size_t ob = (((size_t)s * nch_out + chout) * 48 + fnl) * 1024 + irow;
        *(float4*)&XR_out[ob] = make_float4(y0, y1, y2, y3);
        ushort4 bv;
        bv.x = to_bf16(y0); bv.y = to_bf16(y1); bv.z = to_bf16(y2); bv.w = to_bf16(y3);
        *(ushort4*)&XT_out[ob] = bv;
    }
}

// ---------------------------------------------------------------- spp max over c2 (transposed layout [s][c][48][1024])
__global__ __launch_bounds__(256)
void spp_max_kernel(const float* __restrict__ xr4, float* __restrict__ h0)
{
    const int gw   = (blockIdx.x * 256 + threadIdx.x) >> 6;
    const int lane = threadIdx.x & 63;
    if (gw >= NB * 4 * 385) return;
    const int s    = gw / (4 * 385);
    int rem        = gw - s * (4 * 385);
    const int c    = rem / 385;
    const int cell = rem - c * 385;

    int p1 = 1, base = 0;
    while (p1 < 10 && cell >= base + p1 * p1) { base += p1 * p1; ++p1; }
    const int ci = cell - base;

    int kh = (NN + p1 - 1) / p1;  int ph = kh * p1 - NN; if (ph * 2 > kh) ph = kh / 2;
    int kw = (FF + p1 - 1) / p1;  int pw = kw * p1 - FF; if (pw * 2 > kw) pw = kw / 2;
    const int ow = (FF + 2 * pw - kw) / kw + 1;
    const int oh = (NN + 2 * ph - kh) / kh + 1;
    if (ci >= oh * ow) return;

    const int r = ci / ow, cw = ci - r * ow;
    int r0 = r * kh - ph;  int r1 = r0 + kh; if (r1 > NN) r1 = NN; if (r0 < 0) r0 = 0;
    int c0 = cw * kw - pw; int c1 = c0 + kw; if (c1 > FF) c1 = FF; if (c0 < 0) c0 = 0;

    const float* bp = xr4 + ((size_t)s * 4 + c) * (48 * 1024);
    float m = -3.402823466e38f;
    for (int ff = c0; ff < c1; ++ff) {
        const float* rowp = bp + (size_t)ff * 1024;
        for (int ii = r0 + lane; ii < r1; ii += 64) m = fmaxf(m, rowp[ii]);
    }
#pragma unroll
    for (int o = 32; o >= 1; o >>= 1) m = fmaxf(m, __shfl_xor(m, o, 64));
    if (lane == 0) h0[(size_t)s * LIN_IN + c * 385 + cell] = m;
}

// ---------------------------------------------------------------- fused conv1+conv2+avg pools, strip form
// 30 strips of 34 rows per image; all pool-row-bin boundaries (340,510,680)
// are multiples of 34 -> each strip sits in one row-bin per level.
// 256 threads span the full 1020-col output width (4 cols each, t<255).
// Register-resident sliding windows (3x8 s-rows, 3x2x6 z1-rows), period-3
// static rotation via 3x-unrolled loop. No LDS/barriers in the main loop.
__global__ __launch_bounds__(256, 2)
void conv_pool_strip(const float* __restrict__ sM,
                     const float* __restrict__ cw1, const float* __restrict__ cb1,
                     const float* __restrict__ cw2, const float* __restrict__ cb2,
                     float* __restrict__ h0)
{
    __shared__ float bins[30];   // [5ch][b]: b=0 p1, 1..2 p2(cb2), 3..5 p3(cb3)
    const int ss   = blockIdx.x;     // strip 0..29
    const int simg = blockIdx.y;     // image
    const int tid  = threadIdx.x;
    const int lane = tid & 63;
    const int r0   = ss * 34;
    const int rb2  = (ss >= 15);
    const int rb3  = ss / 10;

    if (tid < 30) bins[tid] = 0.f;
    __syncthreads();

    const int colbase = (tid < 255) ? tid * 4 : 254 * 4;
    const float* sp = sM + (size_t)simg * (NN * NN) + colbase;

    float w1r[18], w2r[90], b1r[2], b2r[5];
#pragma unroll
    for (int i = 0; i < 18; ++i) w1r[i] = cw1[i];
#pragma unroll
    for (int i = 0; i < 90; ++i) w2r[i] = cw2[i];
    b1r[0] = cb1[0]; b1r[1] = cb1[1];
#pragma unroll
    for (int i = 0; i < 5; ++i) b2r[i] = cb2[i];

    float sw[3][8];
    float z1w[3][2][6];
    float acc[5][4];
#pragma unroll
    for (int o = 0; o < 5; ++o)
#pragma unroll
        for (int j = 0; j < 4; ++j) acc[o][j] = 0.f;

#define LOADROW(slot, rabs) do { \
    float4 v0 = *(const float4*)(sp + (size_t)(rabs) * NN); \
    float4 v1 = *(const float4*)(sp + (size_t)(rabs) * NN + 4); \
    sw[slot][0]=v0.x; sw[slot][1]=v0.y; sw[slot][2]=v0.z; sw[slot][3]=v0.w; \
    sw[slot][4]=v1.x; sw[slot][5]=v1.y; sw[slot][6]=v1.z; sw[slot][7]=v1.w; } while(0)

    // Z1ROW(P): compute z1 row rr+2 (P=rr%3) into slot (P+2)%3 from s rows
    // rr+2,rr+3,rr+4 at slots (P+2)%3, P, (P+1)%3.
#define Z1ROW(P) do { \
    _Pragma("unroll") for (int ch = 0; ch < 2; ++ch) { \
      _Pragma("unroll") for (int jj = 0; jj < 6; ++jj) { \
        float a = b1r[ch]; \
        _Pragma("unroll") for (int dc = 0; dc < 3; ++dc) { \
            a += sw[((P)+2)%3][jj+dc] * w1r[ch*9+0+dc]; \
            a += sw[(P)%3    ][jj+dc] * w1r[ch*9+3+dc]; \
            a += sw[((P)+1)%3][jj+dc] * w1r[ch*9+6+dc]; } \
        z1w[((P)+2)%3][ch][jj] = leakyf(a); } } } while(0)

    // Z2ROW(P): z2 row rr from z1 rows rr,rr+1,rr+2 at slots P,(P+1)%3,(P+2)%3
#define Z2ROW(P) do { \
    _Pragma("unroll") for (int o = 0; o < 5; ++o) { \
      _Pragma("unroll") for (int j = 0; j < 4; ++j) { \
        float a = b2r[o]; \
        _Pragma("unroll") for (int ich = 0; ich < 2; ++ich) { \
          _Pragma("unroll") for (int dc = 0; dc < 3; ++dc) { \
            a += z1w[(P)%3    ][ich][j+dc] * w2r[(o*2+ich)*9+0+dc]; \
            a += z1w[((P)+1)%3][ich][j+dc] * w2r[(o*2+ich)*9+3+dc]; \
            a += z1w[((P)+2)%3][ich][j+dc] * w2r[(o*2+ich)*9+6+dc]; } } \
        acc[o][j] += leakyf(a); } } } while(0)

    // prologue: s rows r0..r0+3, z1 rows r0,r0+1
    LOADROW(0, r0 + 0);
    LOADROW(1, r0 + 1);
    LOADROW(2, r0 + 2);
    Z1ROW(1);              // z1 row r0   -> slot 0
    LOADROW(0, r0 + 3);    // s row r0+3  -> slot 0
    Z1ROW(2);              // z1 row r0+1 -> slot 1

#pragma unroll 1
    for (int rr = 0; rr < 33; rr += 3) {
        LOADROW(1, r0 + rr + 4); Z1ROW(0); Z2ROW(0);
        LOADROW(2, r0 + rr + 5); Z1ROW(1); Z2ROW(1);
        LOADROW(0, r0 + rr + 6); Z1ROW(2); Z2ROW(2);
    }
    LOADROW(1, r0 + 37); Z1ROW(0); Z2ROW(0);   // rr = 33

#undef LOADROW
#undef Z1ROW
#undef Z2ROW

    if (tid == 255) {
#pragma unroll
        for (int o = 0; o < 5; ++o)
#pragma unroll
            for (int j = 0; j < 4; ++j) acc[o][j] = 0.f;
    }

    int cb2c[4], cb3c[4];
#pragma unroll
    for (int j = 0; j < 4; ++j) {
        int col = colbase + j;
        int a2 = col / 510; if (a2 > 1) a2 = 1;
        int a3 = col / 340; if (a3 > 2) a3 = 2;
        cb2c[j] = a2; cb3c[j] = a3;
    }

#pragma unroll
    for (int o = 0; o < 5; ++o) {
        float t1 = acc[o][0] + acc[o][1] + acc[o][2] + acc[o][3];
        float pa = 0.f, pb = 0.f, q0 = 0.f, q1 = 0.f, q2 = 0.f;
#pragma unroll
        for (int j = 0; j < 4; ++j) {
            float v = acc[o][j];
            if (cb2c[j] == 0) pa += v; else pb += v;
            if (cb3c[j] == 0) q0 += v; else if (cb3c[j] == 1) q1 += v; else q2 += v;
        }
#pragma unroll
        for (int d = 32; d >= 1; d >>= 1) {
            t1 += __shfl_xor(t1, d, 64);
            pa += __shfl_xor(pa, d, 64);
            pb += __shfl_xor(pb, d, 64);
            q0 += __shfl_xor(q0, d, 64);
            q1 += __shfl_xor(q1, d, 64);
            q2 += __shfl_xor(q2, d, 64);
        }
        if (lane == 0) {
            atomicAdd(&bins[o * 6 + 0], t1);
            atomicAdd(&bins[o * 6 + 1], pa);
            atomicAdd(&bins[o * 6 + 2], pb);
            atomicAdd(&bins[o * 6 + 3], q0);
            atomicAdd(&bins[o * 6 + 4], q1);
            atomicAdd(&bins[o * 6 + 5], q2);
        }
    }
    __syncthreads();
    if (tid < 30) {
        int o = tid / 6, b = tid % 6;
        int off = (b == 0) ? 0 : (b <= 2) ? (1 + rb2 * 2 + (b - 1))
                                          : (5 + rb3 * 3 + (b - 3));
        atomicAdd(h0 + (size_t)simg * LIN_IN + 1540 + o * 14 + off, bins[tid]);
    }
}

__global__ __launch_bounds__(256)
void stru_div_kernel(float* __restrict__ h0)
{
    const int i = blockIdx.x * 256 + threadIdx.x;
    if (i >= NB * 5 * 14) return;
    const int s = i / (5 * 14);
    const int rest = i - s * (5 * 14);
    const int within = rest % 14;
    const float d = (within == 0) ? (1.f / (1020.f * 1020.f))
                  : (within < 5)  ? (1.f / (510.f * 510.f))
                                  : (1.f / (340.f * 340.f));
    h0[(size_t)s * LIN_IN + 1540 + rest] *= d;
}

// ---------------------------------------------------------------- FC
__global__ __launch_bounds__(256)
void fc_kernel(const float* __restrict__ in, const float* __restrict__ W,
               const float* __restrict__ bias, float* __restrict__ out,
               int K, int Nout, int do_leaky)
{
    const int o = (blockIdx.x * 256 + threadIdx.x) >> 6;
    const int lane = threadIdx.x & 63;
    if (o >= Nout) return;
    const float* wrow = W + (size_t)o * K;
    float acc[16];
#pragma unroll
    for (int b = 0; b < 16; ++b) acc[b] = 0.f;
    for (int k0 = 0; k0 < K; k0 += 64) {
        const int kk = k0 + lane;
        const bool in_r = kk < K;
        const float wv = in_r ? wrow[kk] : 0.f;
#pragma unroll
        for (int b = 0; b < 16; ++b) {
            const float hv = in_r ? in[(size_t)b * K + kk] : 0.f;
            acc[b] += wv * hv;
        }
    }
    float res = 0.f;
#pragma unroll
    for (int b = 0; b < 16; ++b) {
        float v = acc[b];
#pragma unroll
        for (int od = 32; od >= 1; od >>= 1) v += __shfl_xor(v, od, 64);
        if (lane == b) res = v;
    }
    if (lane < 16) {
        const float y = res + bias[o];
        out[(size_t)lane * Nout + o] = do_leaky ? leakyf(y) : y;
    }
}

// ---------------------------------------------------------------- launch
extern "C" void kernel_launch(void* const* d_in, const int* in_sizes, int n_in,
                              void* d_out, int out_size, void* d_ws, size_t ws_size,
                              hipStream_t stream)
{
    const float* labels = (const float*)d_in[0];
    const float* sM     = (const float*)d_in[1];
    const float* K1     = (const float*)d_in[2];
    const float* K2     = (const float*)d_in[3];
    const float* cw1    = (const float*)d_in[4];
    const float* cb1    = (const float*)d_in[5];
    const float* cw2    = (const float*)d_in[6];
    const float* cb2    = (const float*)d_in[7];
    const float* W1     = (const float*)d_in[8];
    const float* b1     = (const float*)d_in[9];
    const float* W2     = (const float*)d_in[10];
    const float* b2     = (const float*)d_in[11];
    const float* W3     = (const float*)d_in[12];
    const float* b3     = (const float*)d_in[13];
    const float* W4     = (const float*)d_in[14];
    const float* b4     = (const float*)d_in[15];
    const float* W5     = (const float*)d_in[16];
    const float* b5     = (const float*)d_in[17];

    char* ws = (char*)d_ws;
    uint8_t* codes = (uint8_t*)ws;  ws += (size_t)16 << 20;
    char* ping = ws;                ws += 18874368;   // XT(6.29MB) + XR(12.58MB)
    char* pong = ws;                ws += 18874368;
    float* h0  = (float*)ws;        ws += 103168;
    float* hA  = (float*)ws;        ws += 128000;
    float* hB  = (float*)ws;        ws += 128000;

    uint16_t* XTp = (uint16_t*)ping; float* XRp = (float*)(ping + 6291456);
    uint16_t* XTq = (uint16_t*)pong; float* XRq = (float*)(pong + 6291456);

    hipMemsetAsync(h0, 0, (size_t)NB * LIN_IN * 4, stream);

    codes_kernel<<<2048, 256, 0, stream>>>(sM, codes, 16 * 1024 * 1024 / 4);
    labels_to_xt<<<dim3(16, 4), 256, 0, stream>>>(labels, XTq, XRq);

    wlc_gemm<<<dim3(16, 1, 16), 256, 0, stream>>>(XTq, XRq, XTp, XRp, codes, K1, 0, 1, 1, 2, 0);
    wlc_gemm<<<dim3(16, 1, 16), 256, 0, stream>>>(XTp, XRp, XTq, XRq, codes, K1, 1, 0, 2, 2, 1);
    wlc_gemm<<<dim3(16, 2, 16), 256, 0, stream>>>(XTq, XRq, XTp, XRp, codes, K2, 0, 1, 2, 4, 0);
    wlc_gemm<<<dim3(16, 2, 16), 256, 0, stream>>>(XTp, XRp, XTq, XRq, codes, K2, 1, 0, 4, 4, 1);

    spp_max_kernel<<<6160, 256, 0, stream>>>(XRq, h0);
    conv_pool_strip<<<dim3(30, 16), 256, 0, stream>>>(sM, cw1, cb1, cw2, cb2, h0);
    stru_div_kernel<<<5, 256, 0, stream>>>(h0);

    fc_kernel<<<500, 256, 0, stream>>>(h0, W1, b1, hA, LIN_IN, 2000, 1);
    fc_kernel<<<500, 256, 0, stream>>>(hA, W2, b2, hB, 2000, 2000, 1);
    fc_kernel<<<500, 256, 0, stream>>>(hB, W3, b3, hA, 2000, 2000, 1);
    fc_kernel<<<500, 256, 0, stream>>>(hA, W4, b4, hB, 2000, 2000, 1);
    fc_kernel<<<1,   256, 0, stream>>>(hB, W5, b5, (float*)d_out, 2000, 2, 0);
}